// Round 11
// baseline (572.427 us; speedup 1.0000x reference)
//
#include <hip/hip_runtime.h>
#include <math.h>

typedef unsigned int   uint32;
typedef unsigned short ushort16;
typedef __attribute__((ext_vector_type(8))) short  short8;   // 8 bf16 (MFMA A/B frag)
typedef __attribute__((ext_vector_type(4))) float  floatx4;  // MFMA C/D frag

// Problem dims
#define Bb   512
#define QLn  128
#define ALn  512
#define En   300
#define Fn   400
#define OW   416      // packed output width: 400 real + 16 zero (832 B = 13*64)
#define EPAD 320      // e padded 300 -> 320 per shift
#define NV   50001
#define ECROWS 50176  // 196*256 padded vocab rows
#define ECSTRIDE 2560 // 1280 cols * 2B (3*416 used + 32 pad)

typedef const __attribute__((address_space(1))) unsigned int guint_t;
typedef __attribute__((address_space(3))) unsigned int luint_t;
#define GLDS16(g, l) __builtin_amdgcn_global_load_lds((guint_t*)(g), (luint_t*)(l), 16, 0, 0)

static __device__ __forceinline__ float bf_lo(uint32 u) { return __uint_as_float(u << 16); }
static __device__ __forceinline__ float bf_hi(uint32 u) { return __uint_as_float(u & 0xffff0000u); }
static __device__ __forceinline__ ushort16 f2bf(float f) {
    uint32 u = __float_as_uint(f);
    uint32 r = (u + 0x7fffu + ((u >> 16) & 1u)) >> 16;   // RNE
    return (ushort16)r;
}
static __device__ __forceinline__ uint32 pack2(float a, float b) {
    return (uint32)f2bf(a) | ((uint32)f2bf(b) << 16);
}

// ---------------------------------------------------------------------------
// embcvt: embbf[v][0..320) = bf16(emb[v][0..300)), e>=300 zero.
// ---------------------------------------------------------------------------
__global__ __launch_bounds__(128) void embcvt_kernel(
        const float* __restrict__ emb, char* __restrict__ embbf)
{
    const int r = blockIdx.x, j = threadIdx.x;
    const float* er = emb + (size_t)r * En;
    uint32* orow = (uint32*)(embbf + (size_t)r * 640);
    for (int d = j; d < 160; d += 128) {
        uint32 v = 0;
        if (d < 150) {
            float2 f2v = *(const float2*)(er + 2 * d);
            v = pack2(f2v.x, f2v.y);
        }
        orow[d] = v;
    }
}

// ---------------------------------------------------------------------------
// prep_wt: Wt2[f][p] = W[f][e*3+kk] (p = kk*320+e), bf16, zero pad; bias2.
// Rows f in [400,512) are fully zero (used as zero-rows by ec_gemm pad).
// ---------------------------------------------------------------------------
__global__ __launch_bounds__(256) void prep_wt(
        const float* __restrict__ W, const float* __restrict__ cb,
        ushort16* __restrict__ Wt2, float* __restrict__ bias2)
{
    const int f = blockIdx.x, t = threadIdx.x;
    for (int p2 = t; p2 < 480; p2 += 256) {
        int p = 2 * p2;
        float v0 = 0.f, v1 = 0.f;
        if (f < Fn) {
            int kk = p / EPAD, e = p - kk * EPAD;
            if (e < En)     v0 = W[(size_t)f * 900 + e * 3 + kk];
            if (e + 1 < En) v1 = W[(size_t)f * 900 + (e + 1) * 3 + kk];
        }
        *(uint32*)&Wt2[(size_t)f * 960 + p] = pack2(v0, v1);
    }
    if (t == 0) bias2[f] = (f < Fn) ? cb[f] : 0.f;
}

// ---------------------------------------------------------------------------
// prep_ub: Ub[g][f] = bf16(U[f][g]), [416][416], zero pad both dims.
// ---------------------------------------------------------------------------
__global__ __launch_bounds__(256) void prep_ub(
        const float* __restrict__ U, ushort16* __restrict__ Ub)
{
    const int g = blockIdx.x, t = threadIdx.x;
    uint32* orow = (uint32*)(Ub + (size_t)g * 416);
    for (int f2 = t; f2 < 208; f2 += 256) {
        int f = 2 * f2;
        float v0 = 0.f, v1 = 0.f;
        if (g < Fn) {
            if (f < Fn)     v0 = U[(size_t)f * Fn + g];
            if (f + 1 < Fn) v1 = U[(size_t)(f + 1) * Fn + g];
        }
        orow[f2] = pack2(v0, v1);
    }
}

// ---------------------------------------------------------------------------
// ec_gemm: EC[v][kk*416+f] = sum_e embbf[v][e] * Wt2[f][kk*320+e]  (bf16)
// BYTE-EXACT round-3 structure (78-79us, frozen). Launched as TWO 490-block
// dispatches (vt halves) purely for top-5 observability: 980 blocks @2/CU
// = 2 occupancy rounds either way, so the split is time-neutral, but each
// ~39us dispatch lets the profiler's top-5 expose the largest LOOP kernel.
// ---------------------------------------------------------------------------
__global__ __launch_bounds__(512) void ec_gemm(
        const char* __restrict__ embbf, const char* __restrict__ Wt2,
        char* __restrict__ EC, int vtBase)
{
    __shared__ __align__(16) char As[32768];   // 2 x 256 rows x 64B
    __shared__ __align__(16) char Bs[32768];
    const int t = threadIdx.x, lane = t & 63, w = t >> 6;
    const int v0 = (vtBase + blockIdx.x) * 256, c0 = blockIdx.y * 256;
    const int wr = w >> 2, wc = w & 3;
    const int fm = lane & 15;
    const int cg = ((lane & 3) - ((lane >> 3) & 3)) & 3;
    const int rl = lane >> 2;
    const int chunkOff = (((lane >> 4) + (fm >> 1)) & 3) * 16;

    const char* srcA[2];
    const char* srcB[2];
#pragma unroll
    for (int i = 0; i < 2; ++i) {
        srcA[i] = embbf + (size_t)(v0 + w * 32 + i * 16 + rl) * 640 + cg * 16;
        int n = c0 + w * 32 + i * 16 + rl;
        int kk = n / 416, f = n - kk * 416;
        if (n >= 1248) { kk = 0; f = 508; }   // zero row
        srcB[i] = Wt2 + (size_t)f * 1920 + kk * 640 + cg * 16;
    }
    char* AsW = As + w * 2048;
    char* BsW = Bs + w * 2048;

    floatx4 acc[8][4];
    const floatx4 zz = {0.f, 0.f, 0.f, 0.f};
#pragma unroll
    for (int m = 0; m < 8; ++m)
#pragma unroll
        for (int n = 0; n < 4; ++n) acc[m][n] = zz;

#define ESTG(ko, buf) do {                                                    \
        const int _ko = (ko); const int _bo = (buf) * 16384;                  \
        GLDS16(srcA[0] + _ko, AsW + _bo);                                     \
        GLDS16(srcA[1] + _ko, AsW + _bo + 1024);                              \
        GLDS16(srcB[0] + _ko, BsW + _bo);                                     \
        GLDS16(srcB[1] + _ko, BsW + _bo + 1024);                              \
    } while (0)

    int cur = 0;
    ESTG(0, 0);
    __syncthreads();
    for (int ks = 0; ks < 10; ++ks) {
        const int nxt = cur ^ 1;
        if (ks < 9) ESTG((ks + 1) * 64, nxt);
        short8 af[8], bfv[4];
        const char* Ac = As + cur * 16384;
        const char* Bc = Bs + cur * 16384;
#pragma unroll
        for (int m = 0; m < 8; ++m)
            af[m] = *(const short8*)(Ac + (wr * 128 + m * 16 + fm) * 64 + chunkOff);
#pragma unroll
        for (int n = 0; n < 4; ++n)
            bfv[n] = *(const short8*)(Bc + (wc * 64 + n * 16 + fm) * 64 + chunkOff);
        __builtin_amdgcn_s_setprio(1);
#pragma unroll
        for (int m = 0; m < 8; ++m)
#pragma unroll
            for (int n = 0; n < 4; ++n)
                acc[m][n] = __builtin_amdgcn_mfma_f32_16x16x32_bf16(
                    af[m], bfv[n], acc[m][n], 0, 0, 0);
        __builtin_amdgcn_s_setprio(0);
        __syncthreads();
        cur = nxt;
    }
#undef ESTG

#pragma unroll
    for (int m = 0; m < 8; ++m) {
        const int v = v0 + wr * 128 + m * 16 + ((lane >> 4) * 4);
#pragma unroll
        for (int n = 0; n < 4; ++n) {
            const int col = c0 + wc * 64 + n * 16 + fm;
#pragma unroll
            for (int r = 0; r < 4; ++r)
                *(ushort16*)(EC + (size_t)(v + r) * ECSTRIDE + col * 2) =
                    f2bf(acc[m][n][r]);
        }
    }
}

// ---------------------------------------------------------------------------
// gather: out[b][l][f] = bf16( EC[t(l-1)][0*416+f] + EC[t(l)][1*416+f]
//                            + EC[t(l+1)][2*416+f] + bias[f] )
// One thread per 16B chunk (52/row). Third block region runs pool_b for the
// PREVIOUS chunk (reads only scr; pool_a(i) overwrites scr after gather(i)).
// ---------------------------------------------------------------------------
static __device__ __forceinline__ void gather_one(
        const int* __restrict__ toks, const char* __restrict__ EC,
        const float* __restrict__ bias2, char* __restrict__ outb,
        int id, int L)
{
    const uint32 uid = (uint32)id;
    const int c = (int)(uid % 52u);
    const int r = (int)(uid / 52u);
    const int l = r & (L - 1), b = r / L;   // L is 512 or 128 (pow2)
    const int* tr = toks + (size_t)b * L;
    const int t0 = (l > 0)     ? tr[l - 1] : 0;
    const int t1 = tr[l];
    const int t2 = (l < L - 1) ? tr[l + 1] : 0;
    const uint4 x0 = *(const uint4*)(EC + (size_t)t0 * ECSTRIDE +        c * 16);
    const uint4 x1 = *(const uint4*)(EC + (size_t)t1 * ECSTRIDE +  832 + c * 16);
    const uint4 x2 = *(const uint4*)(EC + (size_t)t2 * ECSTRIDE + 1664 + c * 16);
    const float4 b0 = *(const float4*)(bias2 + c * 8);
    const float4 b1 = *(const float4*)(bias2 + c * 8 + 4);
    uint4 o;
    o.x = pack2(bf_lo(x0.x) + bf_lo(x1.x) + bf_lo(x2.x) + b0.x,
                bf_hi(x0.x) + bf_hi(x1.x) + bf_hi(x2.x) + b0.y);
    o.y = pack2(bf_lo(x0.y) + bf_lo(x1.y) + bf_lo(x2.y) + b0.z,
                bf_hi(x0.y) + bf_hi(x1.y) + bf_hi(x2.y) + b0.w);
    o.z = pack2(bf_lo(x0.z) + bf_lo(x1.z) + bf_lo(x2.z) + b1.x,
                bf_hi(x0.z) + bf_hi(x1.z) + bf_hi(x2.z) + b1.y);
    o.w = pack2(bf_lo(x0.w) + bf_lo(x1.w) + bf_lo(x2.w) + b1.z,
                bf_hi(x0.w) + bf_hi(x1.w) + bf_hi(x2.w) + b1.w);
    *(uint4*)(outb + (size_t)r * 832 + c * 16) = o;
}

static __device__ __forceinline__ float red_sum_256(float v, volatile float* red) {
    int t = threadIdx.x;
    red[t] = v; __syncthreads();
    for (int s = 128; s > 0; s >>= 1) {
        if (t < s) red[t] = red[t] + red[t + s];
        __syncthreads();
    }
    float r = red[0]; __syncthreads();
    return r;
}

static __device__ __forceinline__ void pool_b_body(
        const float* __restrict__ scratch, float* __restrict__ out,
        int b, volatile float* red)
{
    const int t = threadIdx.x;
    float dd = 0.f, qq = 0.f, aam = 0.f;
    if (t < 208) {
        float q0 = 0.f, q1 = 0.f, a0 = 0.f, a1 = 0.f;
#pragma unroll
        for (int qtr = 0; qtr < 4; ++qtr) {
            const float* sc = scratch + ((size_t)b * 4 + qtr) * 832;
            q0 += sc[t]; q1 += sc[208 + t];
            a0 += sc[416 + t]; a1 += sc[624 + t];
        }
        dd  = q0 * a0 + q1 * a1;
        qq  = q0 * q0 + q1 * q1;
        aam = a0 * a0 + a1 * a1;
    }
    dd  = red_sum_256(dd, red);
    qq  = red_sum_256(qq, red);
    aam = red_sum_256(aam, red);
    if (t == 0) {
        float nq = fmaxf(sqrtf(qq), 1e-8f);
        float na = fmaxf(sqrtf(aam), 1e-8f);
        out[b] = dd / (nq * na);
    }
}

#define GQB 1024
#define GAB 4096
__global__ __launch_bounds__(256) void gather_both(
        const int* __restrict__ question, const int* __restrict__ answer,
        const char* __restrict__ EC, const float* __restrict__ bias2,
        char* __restrict__ qb, char* __restrict__ ab, int nb,
        const float* __restrict__ scrPrev, float* __restrict__ outPrev,
        int nbPrev)
{
    __shared__ float red[256];
    const int bx = blockIdx.x, t = threadIdx.x;
    if (bx < GQB) {
        const int total = nb * QLn * 52;
        for (int id = bx * 256 + t; id < total; id += GQB * 256)
            gather_one(question, EC, bias2, qb, id, QLn);
    } else if (bx < GQB + GAB) {
        const int total = nb * ALn * 52;
        for (int id = (bx - GQB) * 256 + t; id < total; id += GAB * 256)
            gather_one(answer, EC, bias2, ab, id, ALn);
    } else {
        const int b = bx - GQB - GAB;
        if (b < nbPrev) pool_b_body(scrPrev, outPrev, b, red);
    }
}

// ---------------------------------------------------------------------------
// qp_gemm (M-split): frozen r10 form (measured win).
// ---------------------------------------------------------------------------
template<int MF, int NF, int BR>
static __device__ __forceinline__ void qp_tile64(
        const char* __restrict__ Qb, const char* __restrict__ Ub,
        char* __restrict__ ob, int col0, char* As, char* Bs)
{
    const int t = threadIdx.x, lane = t & 63, w = t >> 6;   // 4 waves
    const int NWN = (MF == 4) ? 4 : 2;
    const int wr = w / NWN, wc = w % NWN;
    const int fm = lane & 15;
    const int cg = ((lane & 3) - ((lane >> 3) & 3)) & 3;
    const int rl = lane >> 2;
    const int chunkOff = (((lane >> 4) + (fm >> 1)) & 3) * 16;
    const int BUFB = BR * 64;

    const char* srcQ = Qb + (size_t)(w * 16 + rl) * 832 + cg * 16;
    const char* srcB0;
    const char* srcB1 = 0;
    if (BR == 256) {
        srcB0 = Ub + (size_t)(col0 + w * 64 + rl) * 832 + cg * 16;
    } else {
        srcB0 = Ub + (size_t)(col0 + w * 32 + rl) * 832 + cg * 16;
        srcB1 = Ub + (size_t)(col0 + 128 + w * 16 + rl) * 832 + cg * 16;
    }

    floatx4 acc[MF][NF];
    const floatx4 zz = {0.f, 0.f, 0.f, 0.f};
#pragma unroll
    for (int m = 0; m < MF; ++m)
#pragma unroll
        for (int n = 0; n < NF; ++n) acc[m][n] = zz;

#define QSTG(ko, buf) do {                                                    \
        const int _ko = (ko);                                                 \
        GLDS16(srcQ + _ko, As + (buf) * 4096 + w * 1024);                     \
        if (BR == 256) {                                                      \
            GLDS16(srcB0 + _ko,         Bs + (buf) * BUFB + w * 4096);        \
            GLDS16(srcB0 + 13312 + _ko, Bs + (buf) * BUFB + w * 4096 + 1024); \
            GLDS16(srcB0 + 26624 + _ko, Bs + (buf) * BUFB + w * 4096 + 2048); \
            GLDS16(srcB0 + 39936 + _ko, Bs + (buf) * BUFB + w * 4096 + 3072); \
        } else {                                                              \
            GLDS16(srcB0 + _ko,         Bs + (buf) * BUFB + w * 2048);        \
            GLDS16(srcB0 + 13312 + _ko, Bs + (buf) * BUFB + w * 2048 + 1024); \
            if (w < 2) GLDS16(srcB1 + _ko, Bs + (buf) * BUFB + 8192 + w * 1024); \
        }                                                                     \
    } while (0)

    int cur = 0;
    QSTG(0, 0);
    __syncthreads();
    for (int ks = 0; ks < 13; ++ks) {
        const int nxt = cur ^ 1;
        if (ks < 12) QSTG((ks + 1) * 64, nxt);
        short8 af[MF], bfv[NF];
        const char* Ac = As + cur * 4096;
        const char* Bc = Bs + cur * BUFB;
#pragma unroll
        for (int m = 0; m < MF; ++m)
            af[m] = *(const short8*)(Ac + (wr * (MF * 16) + m * 16 + fm) * 64 + chunkOff);
#pragma unroll
        for (int n = 0; n < NF; ++n)
            bfv[n] = *(const short8*)(Bc + (wc * (NF * 16) + n * 16 + fm) * 64 + chunkOff);
        __builtin_amdgcn_s_setprio(1);
#pragma unroll
        for (int m = 0; m < MF; ++m)
#pragma unroll
            for (int n = 0; n < NF; ++n)
                acc[m][n] = __builtin_amdgcn_mfma_f32_16x16x32_bf16(
                    af[m], bfv[n], acc[m][n], 0, 0, 0);
        __builtin_amdgcn_s_setprio(0);
        __syncthreads();
        cur = nxt;
    }
#undef QSTG

#pragma unroll
    for (int m = 0; m < MF; ++m) {
        const int row = wr * (MF * 16) + m * 16 + ((lane >> 4) * 4);
#pragma unroll
        for (int n = 0; n < NF; ++n) {
            const int col = col0 + wc * (NF * 16) + n * 16 + fm;
#pragma unroll
            for (int r = 0; r < 4; ++r)
                *(ushort16*)(ob + (size_t)(row + r) * 832 + col * 2) =
                    f2bf(acc[m][n][r]);
        }
    }
}

__global__ __launch_bounds__(256) void qp_gemm(
        const char* __restrict__ qb, const char* __restrict__ Ub,
        char* __restrict__ qpb, int nb)
{
    __shared__ __align__(16) char As[8192];    // 2 x 64 rows x 64B
    __shared__ __align__(16) char Bs[32768];   // 2 x <=256 rows x 64B
    const int bx = blockIdx.x;
    const int xcd = bx & 7, rest = bx >> 3;
    const int nt = rest & 1, mh = (rest >> 1) & 1, b = (rest >> 2) * 8 + xcd;
    if (b >= nb) return;
    const char* Qb = qb + (size_t)b * 106496 + (size_t)mh * 64 * 832;
    char* ob = qpb + (size_t)b * 106496 + (size_t)mh * 64 * 832;
    if (nt == 0)
        qp_tile64<4, 4, 256>(Qb, Ub, ob, 0, As, Bs);
    else
        qp_tile64<2, 5, 160>(Qb, Ub, ob, 256, As, Bs);
}

// ---------------------------------------------------------------------------
// fused_g (c-quarter split): block (b, cq). G = Qp (full 128 rows) x
// A[cq*128 .. +128]^T, K=416. vs r9's mh-split: A read ONCE per batch (was
// 2x; -110MB total), Qp read 4x (small). LDS 33KB -> 4 blocks/CU (was 3).
// 4 waves; wave w owns A-cols w*32 (NF=2), all 128 Q-rows (MF=8).
// colMg[b][512] now EXACT per column (block owns distinct cols);
// rowPart[b][4][128] partials (pool maxes 4).
// ---------------------------------------------------------------------------
__global__ __launch_bounds__(256) void fused_g(
        const ushort16* __restrict__ Qp,   // [nb][128][416]
        const ushort16* __restrict__ Av,   // [nb][512][416]
        float* __restrict__ rowPart,       // [nb][4][128]
        float* __restrict__ colMg,         // [nb][512]
        int nb)
{
    __shared__ __align__(16) char Qs[16384];    // 2 x 128 x 64B
    __shared__ __align__(16) char Asl[16384];   // 2 x 128 x 64B
    __shared__ float rowM4[128][4];

    const int t = threadIdx.x, lane = t & 63, w = t >> 6;   // 4 waves
    const int bx = blockIdx.x;
    const int xcd = bx & 7, rest = bx >> 3;
    const int cq = rest & 3, b = (rest >> 2) * 8 + xcd;
    if (b >= nb) return;
    const int fm = lane & 15;
    const int cg = ((lane & 3) - ((lane >> 3) & 3)) & 3;
    const int rl = lane >> 2;
    const int chunkOff = (((lane >> 4) + (fm >> 1)) & 3) * 16;

    const char* Qpb = (const char*)Qp + (size_t)b * 106496;
    const char* Ab  = (const char*)Av + (size_t)b * 425984 + (size_t)cq * 128 * 832;
    const char* srcQ0 = Qpb + (size_t)(w * 32 + rl) * 832 + cg * 16;
    const char* srcQ1 = srcQ0 + (size_t)16 * 832;
    const char* srcA0 = Ab + (size_t)(w * 32 + rl) * 832 + cg * 16;
    const char* srcA1 = srcA0 + (size_t)16 * 832;

    floatx4 acc[8][2];
    const floatx4 zz = {0.f, 0.f, 0.f, 0.f};
#pragma unroll
    for (int m = 0; m < 8; ++m)
#pragma unroll
        for (int n = 0; n < 2; ++n) acc[m][n] = zz;

#define FSTG(ko, buf) do {                                                    \
        const int _ko = (ko);                                                 \
        GLDS16(srcQ0 + _ko, Qs  + (buf) * 8192 + w * 2048);                   \
        GLDS16(srcQ1 + _ko, Qs  + (buf) * 8192 + w * 2048 + 1024);            \
        GLDS16(srcA0 + _ko, Asl + (buf) * 8192 + w * 2048);                   \
        GLDS16(srcA1 + _ko, Asl + (buf) * 8192 + w * 2048 + 1024);            \
    } while (0)

    int cur = 0;
    FSTG(0, 0);
    __syncthreads();

    for (int ks = 0; ks < 13; ++ks) {
        const int nxt = cur ^ 1;
        if (ks < 12) FSTG((ks + 1) * 64, nxt);

        short8 qa[8], aa_[2];
        const char* Qc = Qs + cur * 8192;
        const char* Ac = Asl + cur * 8192;
#pragma unroll
        for (int m = 0; m < 8; ++m)
            qa[m] = *(const short8*)(Qc + (m * 16 + fm) * 64 + chunkOff);
#pragma unroll
        for (int n = 0; n < 2; ++n)
            aa_[n] = *(const short8*)(Ac + (w * 32 + n * 16 + fm) * 64 + chunkOff);
        __builtin_amdgcn_s_setprio(1);
#pragma unroll
        for (int m = 0; m < 8; ++m)
#pragma unroll
            for (int n = 0; n < 2; ++n)
                acc[m][n] = __builtin_amdgcn_mfma_f32_16x16x32_bf16(
                    qa[m], aa_[n], acc[m][n], 0, 0, 0);
        __builtin_amdgcn_s_setprio(0);
        __syncthreads();
        cur = nxt;
    }
#undef FSTG

    // rowMax partial (max over this wave's 32 A-cols) -> rowM4[row][w]
#pragma unroll
    for (int m = 0; m < 8; ++m)
#pragma unroll
        for (int r = 0; r < 4; ++r) {
            float v = fmaxf(acc[m][0][r], acc[m][1][r]);
            v = fmaxf(v, __shfl_xor(v, 1));
            v = fmaxf(v, __shfl_xor(v, 2));
            v = fmaxf(v, __shfl_xor(v, 4));
            v = fmaxf(v, __shfl_xor(v, 8));
            if (fm == 0) rowM4[m * 16 + (lane >> 4) * 4 + r][w] = v;
        }
    // colMax (exact): wave owns cols cq*128 + w*32 + n*16 + fm
#pragma unroll
    for (int n = 0; n < 2; ++n) {
        float v = -1e30f;
#pragma unroll
        for (int m = 0; m < 8; ++m)
#pragma unroll
            for (int r = 0; r < 4; ++r) v = fmaxf(v, acc[m][n][r]);
        v = fmaxf(v, __shfl_xor(v, 16));
        v = fmaxf(v, __shfl_xor(v, 32));
        if (lane < 16)
            colMg[(size_t)b * 512 + cq * 128 + w * 32 + n * 16 + lane] = v;
    }
    __syncthreads();
    if (t < 128)
        rowPart[((size_t)b * 4 + cq) * 128 + t] =
            fmaxf(fmaxf(rowM4[t][0], rowM4[t][1]),
                  fmaxf(rowM4[t][2], rowM4[t][3]));
}

// ---------------------------------------------------------------------------
// pool_a: r9 form adapted to new rowPart[4]/colMg-exact shapes.
// ---------------------------------------------------------------------------
static __device__ __forceinline__ float red_max_512(float v, volatile float* red) {
    int t = threadIdx.x;
    red[t] = v; __syncthreads();
    for (int s = 256; s > 0; s >>= 1) {
        if (t < s) red[t] = fmaxf(red[t], red[t + s]);
        __syncthreads();
    }
    float r = red[0]; __syncthreads();
    return r;
}
static __device__ __forceinline__ float red_sum_512(float v, volatile float* red) {
    int t = threadIdx.x;
    red[t] = v; __syncthreads();
    for (int s = 256; s > 0; s >>= 1) {
        if (t < s) red[t] = red[t] + red[t + s];
        __syncthreads();
    }
    float r = red[0]; __syncthreads();
    return r;
}

__global__ __launch_bounds__(512) void pool_a(
        const ushort16* __restrict__ Qv,   // [nb][128][416]
        const ushort16* __restrict__ Av,   // [nb][512][416]
        const float* __restrict__ rowPart, // [nb][4][128]
        const float* __restrict__ colMg,   // [nb][512]
        float* __restrict__ scratch,       // [nb][4][4][208]
        int nb)
{
    __shared__ float colv[ALn];
    __shared__ float roq[QLn];
    __shared__ float red[512];
    __shared__ float part[2][4][208];
    const int t = threadIdx.x, bx = blockIdx.x;
    const int qtr = bx & 3, b = bx >> 2;

    float v = -1e30f;
    if (t < QLn) {
        const float* rp = rowPart + (size_t)b * 512;
        v = tanhf(fmaxf(fmaxf(rp[t], rp[128 + t]),
                        fmaxf(rp[256 + t], rp[384 + t])));
    }
    float vmax = red_max_512(v, red);
    float ex = (t < QLn) ? __expf(v - vmax) : 0.f;
    float ssum = red_sum_512(ex, red);
    if (t < QLn) roq[t] = ex / ssum;

    float cv = tanhf(colMg[(size_t)b * 512 + t]);
    float cmax = red_max_512(cv, red);
    float e0 = __expf(cv - cmax);
    float csum = red_sum_512(e0, red);
    colv[t] = e0 / csum;
    __syncthreads();

    if (t < 416) {
        const int half = t / 208, c = t - half * 208;
        float rq0 = 0.f, rq1 = 0.f, ra0 = 0.f, ra1 = 0.f;
        const uint32* Qb32 = (const uint32*)((const char*)Qv + (size_t)b * 106496);
        const int q0r = qtr * 32 + half * 16;
#pragma unroll 4
        for (int q = q0r; q < q0r + 16; ++q) {
            float wv = roq[q];
            uint32 u = Qb32[q * 208 + c];
            rq0 = fmaf(bf_lo(u), wv, rq0);
            rq1 = fmaf(bf_hi(u), wv, rq1);
        }
        const uint32* Ab32 = (const uint32*)((const char*)Av + (size_t)b * 425984);
        const int a0r = qtr * 128 + half * 64;
#pragma unroll 4
        for (int a = a0r; a < a0r + 64; ++a) {
            float wv = colv[a];
            uint32 u = Ab32[a * 208 + c];
            ra0 = fmaf(bf_lo(u), wv, ra0);
            ra1 = fmaf(bf_hi(u), wv, ra1);
        }
        part[half][0][c] = rq0; part[half][1][c] = rq1;
        part[half][2][c] = ra0; part[half][3][c] = ra1;
    }
    __syncthreads();

    if (t < 208) {
        float* sc = scratch + ((size_t)b * 4 + qtr) * 832;
        sc[t]       = part[0][0][t] + part[1][0][t];
        sc[208 + t] = part[0][1][t] + part[1][1][t];
        sc[416 + t] = part[0][2][t] + part[1][2][t];
        sc[624 + t] = part[0][3][t] + part[1][3][t];
    }
}

// pool_b standalone (used once for the final chunk).
__global__ __launch_bounds__(256) void pool_b(
        const float* __restrict__ scratch, float* __restrict__ out, int nb)
{
    __shared__ float red[256];
    pool_b_body(scratch, out, blockIdx.x, red);
}

// ---------------------------------------------------------------------------
// launch — ws: [Wt2 | bias2 | Ub | EC | overlay{embbf | per-chunk bufs}]
// per-batch aux: rowPart 2KB + colMg 2KB + scratch 13312B <= MXB 20480.
// ---------------------------------------------------------------------------
extern "C" void kernel_launch(void* const* d_in, const int* in_sizes, int n_in,
                              void* d_out, int out_size, void* d_ws, size_t ws_size,
                              hipStream_t stream)
{
    const int*   question = (const int*)d_in[0];
    const int*   answer   = (const int*)d_in[1];
    const float* emb      = (const float*)d_in[2];
    const float* conv_w   = (const float*)d_in[3];
    const float* conv_b   = (const float*)d_in[4];
    const float* U        = (const float*)d_in[5];
    float* out = (float*)d_out;
    char* ws = (char*)d_ws;

    const size_t WT2B   = (size_t)512 * 960 * 2;             // 983,040
    const size_t UBB    = (size_t)416 * 416 * 2;             // 346,112
    const size_t ECB    = (size_t)ECROWS * ECSTRIDE;         // 128,450,560
    const size_t FIXED0 = WT2B + 2048 + UBB + ECB;           // 129,781,760
    const size_t QB     = (size_t)QLn * OW * 2;              // 106,496
    const size_t AB     = (size_t)ALn * OW * 2;              // 425,984
    const size_t MXB    = 20480;
    const size_t PER_B  = 2 * QB + AB + MXB;                 // 659,456

    size_t avail = (ws_size > FIXED0) ? (ws_size - FIXED0) : 0;
    int CB = (int)(avail / PER_B);
    if (CB > Bb) CB = Bb;
    if (CB < 1)  CB = 1;
    int nch = (Bb + CB - 1) / CB;
    int CBe = (Bb + nch - 1) / nch;      // balanced chunk size (<= CB)

    char*  wt2   = ws;
    float* bias2 = (float*)(ws + WT2B);
    char*  ub    = ws + WT2B + 2048;
    char*  EC    = ws + WT2B + 2048 + UBB;
    char*  embbf = ws + FIXED0;           // overlay: used only for ec_gemm
    char*  qb    = ws + FIXED0;           // overlay after ec_gemm completes
    char*  qpb   = qb  + (size_t)CB * QB;
    char*  ab    = qpb + (size_t)CB * QB;
    float* rowP  = (float*)(ab + (size_t)CB * AB);
    float* colM  = rowP + (size_t)CB * 512;
    float* scr   = colM + (size_t)CB * 512;

    embcvt_kernel<<<NV, 128, 0, stream>>>(emb, embbf);
    prep_wt<<<512, 256, 0, stream>>>(conv_w, conv_b, (ushort16*)wt2, bias2);
    prep_ub<<<416, 256, 0, stream>>>(U, (ushort16*)ub);
    ec_gemm<<<dim3(98, 5), 512, 0, stream>>>(embbf, wt2, EC, 0);
    ec_gemm<<<dim3(98, 5), 512, 0, stream>>>(embbf, wt2, EC, 98);

    int prevNb = 0;
    float* prevOut = out;
    for (int b0 = 0; b0 < Bb; b0 += CBe) {
        int nb = (Bb - b0 < CBe) ? (Bb - b0) : CBe;
        int nb8 = (nb + 7) / 8;
        gather_both<<<GQB + GAB + prevNb, 256, 0, stream>>>(
            question + (size_t)b0 * QLn, answer + (size_t)b0 * ALn,
            EC, bias2, qb, ab, nb, scr, prevOut, prevNb);
        qp_gemm<<<nb8 * 32, 256, 0, stream>>>(qb, ub, qpb, nb);
        fused_g<<<nb8 * 32, 256, 0, stream>>>((const ushort16*)qpb, (const ushort16*)ab,
                                              rowP, colM, nb);
        pool_a<<<nb * 4, 512, 0, stream>>>((const ushort16*)qb, (const ushort16*)ab,
                                           rowP, colM, scr, nb);
        prevNb = nb;
        prevOut = out + b0;
    }
    pool_b<<<prevNb, 256, 0, stream>>>(scr, prevOut, prevNb);
}